// Round 16
// baseline (556.218 us; speedup 1.0000x reference)
//
#include <hip/hip_runtime.h>
#include <hip/hip_bf16.h>
#include <math.h>

typedef unsigned short u16;
typedef unsigned int   u32;
typedef __attribute__((ext_vector_type(8))) short bf16x8;
typedef __attribute__((ext_vector_type(4))) float f32x4;
typedef __attribute__((ext_vector_type(16))) float f32x16;
typedef __attribute__((ext_vector_type(4))) u32 u32x4;

#define NSIDE  240
#define NPIX   57600
#define DMODEL 256
#define NHEAD  8
#define HDIM   32
#define LWIN   20
#define NWIN   12
#define FF     400
#define DFFN   2048
#define BTAB   39   // 2*LW-1
#define LOG2E  1.4426950408889634f
#define QSCALE 0.2550773933046f   // 32^-0.5 * log2(e)

// ---- ws layout (bytes) ----
#define OFF_QKVW  0u           // 768*256 bf16 (plain)
#define OFF_OUTW  393216u      // 256*256 bf16 (plain)
#define OFF_W1    524288u      // 2048*256 bf16 (FRAGMENT order)
#define OFF_W2    1572864u     // 256*2048 bf16 (FRAGMENT order)
#define OFF_FLAG  2621440u
#define OFF_WANY  2621504u     // 144 int
#define OFF_WMASK 2622080u     // 144*13 u32
#define OFF_NM    2629568u     // 57600 B
#define OFF_A     2687488u     // 57600*256 bf16: ln1out/ln2out plain [pix][ch]; attnout head-major [h][pix][32]
#define OFF_B     32178688u    // qkv PLANES bf16 [24][NPIX][32]; later x1 f32 [256][NPIX]

__device__ __forceinline__ float bf2f(u16 u){
  union { float f; u32 i; } v; v.i = ((u32)u) << 16; return v.f;
}
__device__ __forceinline__ float bflo(u32 u){
  union { float f; u32 i; } v; v.i = u << 16; return v.f;
}
__device__ __forceinline__ float bfhi(u32 u){
  union { float f; u32 i; } v; v.i = u & 0xffff0000u; return v.f;
}
__device__ __forceinline__ u16 f2bf(float f){
  union { float f; u32 i; } v; v.f = f;
  u32 r = v.i + 0x7fffu + ((v.i >> 16) & 1u);
  return (u16)(r >> 16);
}
__device__ __forceinline__ u32 pkbf(float a, float b){
  float2 f2; f2.x = a; f2.y = b;
  __hip_bfloat162 h = __float22bfloat162_rn(f2);
  union { __hip_bfloat162 h; u32 u; } c; c.h = h; return c.u;
}
__device__ __forceinline__ void gload16(const void* g, void* l){
  __builtin_amdgcn_global_load_lds((const __attribute__((address_space(1))) u32*)g,
                                   (__attribute__((address_space(3))) u32*)l, 16, 0, 0);
}
__device__ __forceinline__ void gload16nt(const void* g, void* l){
  __builtin_amdgcn_global_load_lds((const __attribute__((address_space(1))) u32*)g,
                                   (__attribute__((address_space(3))) u32*)l, 16, 0, 2);
}

// ---------------- prep: f32 -> bf16 weight converts ----------------
__global__ void cvt_kernel(const float* __restrict__ in, u16* __restrict__ out, int n){
  int i = blockIdx.x * 256 + threadIdx.x;
  if (i < n) out[i] = f2bf(in[i]);
}
// W1 [2048f][256k] -> fragment order
__global__ void cvt_w1T(const float* __restrict__ in, u16* __restrict__ out){
  int i = blockIdx.x * 256 + threadIdx.x;   // 2048*256
  int f = i >> 8, k = i & 255;
  int lane = (f & 15) | (((k >> 3) & 3) << 4);
  size_t dst = ((size_t)((f >> 4) * 8 + (k >> 5)) * 64 + lane) * 8 + (k & 7);
  out[dst] = f2bf(in[i]);
}
// W2 [256o][2048f] -> fragment order
__global__ void cvt_w2T(const float* __restrict__ in, u16* __restrict__ out){
  int i = blockIdx.x * 256 + threadIdx.x;   // 256*2048
  int o = i >> 11, f = i & 2047;
  int lane = (o & 15) | (((f >> 3) & 3) << 4);
  size_t dst = ((size_t)((o >> 4) * 64 + (f >> 5)) * 64 + lane) * 8 + (f & 7);
  out[dst] = f2bf(in[i]);
}

// ---------------- mask dtype detect + normalize ----------------
__global__ void zero_flag(int* __restrict__ flag){ *flag = 0; }
__global__ void detect_mask(const unsigned char* __restrict__ m, int* __restrict__ flag){
  int p = blockIdx.x * 256 + threadIdx.x;
  int i = p / NSIDE, j = p - i * NSIDE;
  int a = (m[p] != 0), b = (m[j * NSIDE + i] != 0);
  unsigned long long ball = __ballot(a != b);
  if ((threadIdx.x & 63) == 0 && ball) atomicOr(flag, 1);
}
__global__ void norm_mask(const void* __restrict__ m, const int* __restrict__ flag,
                          unsigned char* __restrict__ nm){
  int p = blockIdx.x * 256 + threadIdx.x;
  int v;
  if (*flag) v = (((const int*)m)[p] != 0);
  else       v = (((const unsigned char*)m)[p] != 0);
  nm[p] = (unsigned char)v;
}

// ---------------- per-window mask bitmaps (with full-window reset) ----------------
__global__ void wmask_kernel(const unsigned char* __restrict__ nm,
                             u32* __restrict__ wmask, int* __restrict__ wany){
  int w = blockIdx.x;
  int wi = w / NWIN, wj = w % NWIN;
  __shared__ u32 bits[13];
  __shared__ int cnt;
  int t = threadIdx.x;
  if (t < 13) bits[t] = 0;
  if (t == 0) cnt = 0;
  __syncthreads();
  if (t < FF){
    int pj = (wi * LWIN + t / LWIN) * NSIDE + wj * LWIN + (t % LWIN);
    if (nm[pj]){ atomicOr(&bits[t >> 5], 1u << (t & 31)); atomicAdd(&cnt, 1); }
  }
  __syncthreads();
  int full = (cnt == FF);
  if (t < 13) wmask[w * 13 + t] = full ? 0u : bits[t];
  if (t == 0) wany[w] = (cnt > 0 && !full) ? 1 : 0;
}

// ---------------- LayerNorm over channels -> X^T [NPIX][256] bf16, PLAIN ----------------
__global__ __launch_bounds__(256) void ln_kernel(const float* __restrict__ x,
                          const float* __restrict__ g, const float* __restrict__ b,
                          u16* __restrict__ out){
  int p = blockIdx.x * 256 + threadIdx.x;
  float s = 0.f, s2 = 0.f;
  for (int c = 0; c < DMODEL; c++){
    float v = x[c * NPIX + p];
    s += v; s2 += v * v;
  }
  float m = s * (1.f / DMODEL);
  float var = s2 * (1.f / DMODEL) - m * m;
  float inv = rsqrtf(var + 1e-5f);
  u16* orow = out + (size_t)p * DMODEL;
  for (int c0 = 0; c0 < DMODEL; c0 += 8){
    u32 wq[4];
    #pragma unroll
    for (int q = 0; q < 4; q++){
      int c = c0 + 2 * q;
      float v0 = (x[c * NPIX + p] - m) * inv * g[c] + b[c];
      float v1 = (x[(c + 1) * NPIX + p] - m) * inv * g[c + 1] + b[c + 1];
      wq[q] = pkbf(v0, v1);
    }
    uint4 st; st.x = wq[0]; st.y = wq[1]; st.z = wq[2]; st.w = wq[3];
    *(uint4*)&orow[c0] = st;
  }
}

// ---------------- MFMA GEMM: C = W[M][256] * X^T ----------------
// 1D grid (MB*450): m0 = (bid%MB)*128, n0 = (bid/MB)*128 -> temporal X-tile L2 reuse.
// XHM=0: X plain [pix][256]. XHM=1: X head-major [h][pix][32] (attnout).
// EPI 1: +bias+res -> f32 [M][NPIX];
// EPI 2: +bias, q-scale, -> bf16 head-major PLANES [plane*8+h][pix][32] via LDS transpose
template<int EPI, int XHM, int MB>
__global__ __launch_bounds__(256) void gemm_nt(const u16* __restrict__ W,
    const u16* __restrict__ Xt, const float* __restrict__ bias,
    const float* __restrict__ res, void* __restrict__ outp){
  __shared__ u16 SM[128 * 128];       // Ws=SM[0:8192], Xs=SM[8192:16384]; epilogue CT
  u16* Ws = SM;
  u16* Xs = SM + 8192;
  int t = threadIdx.x, wv = t >> 6, ln = t & 63;
  int bid = blockIdx.x;
  int m0 = (bid % MB) * 128, n0 = (bid / MB) * 128;
  int wr = wv >> 1, wc = wv & 1;
  f32x4 acc[4][4];
  #pragma unroll
  for (int r = 0; r < 4; r++)
    #pragma unroll
    for (int c = 0; c < 4; c++) acc[r][c] = (f32x4)0.f;
  const char* Wb = (const char*)W;
  const char* Xb = (const char*)Xt;
  for (int k0 = 0; k0 < 256; k0 += 64){
    #pragma unroll
    for (int i = 0; i < 4; i++){
      int cb = i * 256 + wv * 64;          // wave-uniform 16B-chunk base
      int idx = cb + ln;
      int row = idx >> 3, cc = idx & 7;    // 8 chunks (128B) per row
      int cc2 = cc ^ (row & 7);
      gload16(Wb + (size_t)(m0 + row) * 512 + k0 * 2 + (cc2 << 4), (char*)Ws + cb * 16);
      if (XHM){
        int head = (k0 >> 5) + (cc2 >> 2);
        gload16(Xb + ((size_t)head * NPIX + n0 + row) * 64 + ((cc2 & 3) << 4),
                (char*)Xs + cb * 16);
      } else {
        gload16(Xb + (size_t)(n0 + row) * 512 + k0 * 2 + (cc2 << 4), (char*)Xs + cb * 16);
      }
    }
    __syncthreads();
    #pragma unroll
    for (int kk = 0; kk < 64; kk += 32){
      int kidx = kk + (ln >> 4) * 8;
      int swz = (ln & 7) << 3;
      bf16x8 af[4], bfr[4];
      #pragma unroll
      for (int r = 0; r < 4; r++){
        int row = wr * 64 + r * 16 + (ln & 15);
        af[r] = *(const bf16x8*)&Ws[row * 64 + (kidx ^ swz)];
      }
      #pragma unroll
      for (int c = 0; c < 4; c++){
        int row = wc * 64 + c * 16 + (ln & 15);
        bfr[c] = *(const bf16x8*)&Xs[row * 64 + (kidx ^ swz)];
      }
      #pragma unroll
      for (int r = 0; r < 4; r++)
        #pragma unroll
        for (int c = 0; c < 4; c++)
          acc[r][c] = __builtin_amdgcn_mfma_f32_16x16x32_bf16(af[r], bfr[c], acc[r][c], 0, 0, 0);
    }
    __syncthreads();
  }
  if (EPI == 2){
    float sc = (m0 < 256) ? QSCALE : 1.0f;
    #pragma unroll
    for (int r = 0; r < 4; r++){
      int mo0 = wr * 64 + r * 16 + (ln >> 4) * 4;
      f32x4 bv = *(const f32x4*)&bias[m0 + mo0];
      #pragma unroll
      for (int c = 0; c < 4; c++){
        int no = wc * 64 + c * 16 + (ln & 15);
        uint2 pk;
        pk.x = pkbf((acc[r][c][0] + bv[0]) * sc, (acc[r][c][1] + bv[1]) * sc);
        pk.y = pkbf((acc[r][c][2] + bv[2]) * sc, (acc[r][c][3] + bv[3]) * sc);
        *(uint2*)&SM[no * 128 + mo0] = pk;
      }
    }
    __syncthreads();
    u16* ob = (u16*)outp;
    int plane8 = (m0 >> 8) * 8 + ((m0 & 255) >> 5);   // base plane index (q/k/v × head)
    #pragma unroll
    for (int it = 0; it < 8; it++){
      int idx = t + it * 256;
      int pr = idx >> 4, ch = idx & 15;
      int hl = ch >> 2;                  // local head 0..3
      int off = (ch & 3) * 8;            // within-head u16 offset
      uint4 v = *(const uint4*)&SM[pr * 128 + ch * 8];
      *(uint4*)&ob[((size_t)(plane8 + hl) * NPIX + n0 + pr) * 32 + off] = v;
    }
  } else {
    #pragma unroll
    for (int r = 0; r < 4; r++){
      int mo0 = m0 + wr * 64 + r * 16 + (ln >> 4) * 4;
      f32x4 bv = *(const f32x4*)&bias[mo0];
      #pragma unroll
      for (int c = 0; c < 4; c++){
        int no = n0 + wc * 64 + c * 16 + (ln & 15);
        #pragma unroll
        for (int q = 0; q < 4; q++){
          float v = acc[r][c][q] + bv[q];
          size_t oi = (size_t)(mo0 + q) * NPIX + no;
          ((float*)outp)[oi] = v + res[oi];
        }
      }
    }
  }
}

// ---------------- MFMA windowed attention: 512 threads (8 waves), bias from LDS ----------------
// 1D grid 1152; h=bid&7, w=bid>>3. 8 waves share one K/V/bs stage -> 16 waves/CU at
// the same LDS footprint (2 blocks/CU). Bias via identity xj*39+yj = j + 19*xj.
// Output head-major [h][pix][32].
__global__ __launch_bounds__(512, 4) void attn_kernel(
    const u16* __restrict__ qkvP, const float* __restrict__ relb,
    const u32* __restrict__ wmask, const int* __restrict__ wany,
    u16* __restrict__ out)
{
  __shared__ u16 Ks[400 * 32];       // 64B rows; chunk c holds K[j][c ^ (j&3)]
  __shared__ u16 Vs[32 * 420];       // [d][420]; cols 400..415 zeroed
  __shared__ float bs[BTAB * BTAB];  // shifted: bs[a*39+b] = log2e*rel[(a+20)%39][(b+20)%39]
  int bid = blockIdx.x;
  int h = bid & 7, w = bid >> 3;
  int wi = w / NWIN, wj = w % NWIN;
  int t = threadIdx.x, wv = t >> 6, ln = t & 63;
  const char* kpl = (const char*)qkvP + (size_t)(8 + h) * NPIX * 64;
  const u16*  vpl = qkvP + (size_t)(16 + h) * NPIX * 32;
  const u16*  qpl = qkvP + (size_t)h * NPIX * 32;
  // ---- stage bias table ----
  for (int e = t; e < BTAB * BTAB; e += 512){
    int a = e / BTAB, b = e - a * BTAB;
    int r0 = a + 20; if (r0 >= BTAB) r0 -= BTAB;
    int r1 = b + 20; if (r1 >= BTAB) r1 -= BTAB;
    bs[e] = LOG2E * relb[(r0 * BTAB + r1) * NHEAD + h];
  }
  // ---- stage K ----
  #pragma unroll
  for (int it = 0; it < 4; it++){
    int base = it * 512 + wv * 64;
    if (base < 1600){
      int idx = base + ln;
      int j = idx >> 2, c = idx & 3;
      int pj = (wi * LWIN + j / LWIN) * NSIDE + wj * LWIN + (j % LWIN);
      gload16nt(kpl + (size_t)pj * 64 + ((c ^ (j & 3)) << 4), (char*)Ks + base * 16);
    }
  }
  // ---- stage V transposed: j-pair u32 writes ----
  #pragma unroll
  for (int it = 0; it < 2; it++){
    int idx = t + it * 512;
    if (idx >= 832) break;               // 208 j-pairs x 4 channel-chunks
    int jp = idx >> 2, c = idx & 3;
    int j0 = jp * 2;
    int d0 = c * 8;
    u32 a0 = 0, a1 = 0, a2 = 0, a3 = 0, b0 = 0, b1 = 0, b2 = 0, b3 = 0;
    if (j0 < FF){                        // FF even: j0 < FF implies j0+1 < FF
      int pj0 = (wi * LWIN + j0 / LWIN) * NSIDE + wj * LWIN + (j0 % LWIN);
      int j1 = j0 + 1;
      int pj1 = (wi * LWIN + j1 / LWIN) * NSIDE + wj * LWIN + (j1 % LWIN);
      u32x4 va = __builtin_nontemporal_load((const u32x4*)&vpl[(size_t)pj0 * 32 + c * 8]);
      u32x4 vb = __builtin_nontemporal_load((const u32x4*)&vpl[(size_t)pj1 * 32 + c * 8]);
      a0 = va[0]; a1 = va[1]; a2 = va[2]; a3 = va[3];
      b0 = vb[0]; b1 = vb[1]; b2 = vb[2]; b3 = vb[3];
    }
    *(u32*)&Vs[(d0 + 0) * 420 + j0] = (a0 & 0xffffu) | (b0 << 16);
    *(u32*)&Vs[(d0 + 1) * 420 + j0] = (a0 >> 16) | (b0 & 0xffff0000u);
    *(u32*)&Vs[(d0 + 2) * 420 + j0] = (a1 & 0xffffu) | (b1 << 16);
    *(u32*)&Vs[(d0 + 3) * 420 + j0] = (a1 >> 16) | (b1 & 0xffff0000u);
    *(u32*)&Vs[(d0 + 4) * 420 + j0] = (a2 & 0xffffu) | (b2 << 16);
    *(u32*)&Vs[(d0 + 5) * 420 + j0] = (a2 >> 16) | (b2 & 0xffff0000u);
    *(u32*)&Vs[(d0 + 6) * 420 + j0] = (a3 & 0xffffu) | (b3 << 16);
    *(u32*)&Vs[(d0 + 7) * 420 + j0] = (a3 >> 16) | (b3 & 0xffff0000u);
  }
  __syncthreads();
  int lane31 = ln & 31, hi = ln >> 5;
  int anym = wany[w];
  for (int it8 = wv; it8 < 13; it8 += 8){
    int i = it8 * 32 + lane31;
    int ic = i < FF ? i : FF - 1;
    int xi = ic / LWIN, yi = ic - xi * LWIN;
    int pi = (wi * LWIN + xi) * NSIDE + wj * LWIN + yi;
    const float* bsc = bs + (19 - xi) * BTAB + (19 - yi);
    bf16x8 qf0 = __builtin_nontemporal_load((const bf16x8*)&qpl[(size_t)pi * 32 + hi * 8]);
    bf16x8 qf1 = __builtin_nontemporal_load((const bf16x8*)&qpl[(size_t)pi * 32 + 16 + hi * 8]);
    float m = -3e38f, lsum = 0.f;
    f32x16 o;
    #pragma unroll
    for (int r = 0; r < 16; r++) o[r] = 0.f;
    for (int jt = 0; jt < 13; jt++){
      // C-init = bias fragment via LDS gather: idx = j + 19*(j/20)
      f32x16 acc;
      int jbase = jt * 32 + 4 * hi;
      #pragma unroll
      for (int r = 0; r < 16; r++){
        int j = jbase + (r & 3) + 8 * (r >> 2);
        int jc2 = j < FF ? j : 0;
        int xj = jc2 / LWIN;
        float bv = bsc[jc2 + xj * 19];
        acc[r] = (j < FF) ? bv : -1e30f;
      }
      int jb0 = jt * 32 + lane31;
      int jrc = jb0 < FF ? jb0 : FF - 1;
      const char* kb = (const char*)Ks + jrc * 64;
      bf16x8 kf0 = *(const bf16x8*)(kb + ((hi ^ (jrc & 3)) << 4));
      bf16x8 kf1 = *(const bf16x8*)(kb + (((2 + hi) ^ (jrc & 3)) << 4));
      acc = __builtin_amdgcn_mfma_f32_32x32x16_bf16(kf0, qf0, acc, 0, 0, 0);
      acc = __builtin_amdgcn_mfma_f32_32x32x16_bf16(kf1, qf1, acc, 0, 0, 0);
      if (anym){
        u32 mb = wmask[w * 13 + jt];
        if (mb){
          #pragma unroll
          for (int r = 0; r < 16; r++){
            int jb = (r & 3) + 8 * (r >> 2) + 4 * hi;
            if ((mb >> jb) & 1) acc[r] = -1e30f;
          }
        }
      }
      float tm = acc[0];
      #pragma unroll
      for (int r = 1; r < 16; r++) tm = fmaxf(tm, acc[r]);
      tm = fmaxf(tm, __shfl_xor(tm, 32));
      if (tm > m + 6.f){
        float sc = exp2f(m - tm);
        lsum *= sc;
        #pragma unroll
        for (int r = 0; r < 16; r++) o[r] *= sc;
        m = tm;
      }
      float ls = 0.f;
      #pragma unroll
      for (int r = 0; r < 16; r++){ float pv = exp2f(acc[r] - m); acc[r] = pv; ls += pv; }
      lsum += ls;
      u32 x01 = pkbf(acc[0], acc[1]), x23 = pkbf(acc[2], acc[3]);
      u32 x45 = pkbf(acc[4], acc[5]), x67 = pkbf(acc[6], acc[7]);
      u32 y01 = __shfl_xor(x01, 32), y23 = __shfl_xor(x23, 32);
      u32 y45 = __shfl_xor(x45, 32), y67 = __shfl_xor(x67, 32);
      union { u32 u[4]; bf16x8 v; } f0;
      f0.u[0] = hi ? y45 : x01; f0.u[1] = hi ? y67 : x23;
      f0.u[2] = hi ? x45 : y01; f0.u[3] = hi ? x67 : y23;
      bf16x8 vf0 = *(const bf16x8*)&Vs[lane31 * 420 + jt * 32 + hi * 8];
      o = __builtin_amdgcn_mfma_f32_32x32x16_bf16(vf0, f0.v, o, 0, 0, 0);
      if (jt < 12){
        u32 x89 = pkbf(acc[8], acc[9]),   xab = pkbf(acc[10], acc[11]);
        u32 xcd2 = pkbf(acc[12], acc[13]), xef = pkbf(acc[14], acc[15]);
        u32 y89 = __shfl_xor(x89, 32), yab = __shfl_xor(xab, 32);
        u32 ycd = __shfl_xor(xcd2, 32), yef = __shfl_xor(xef, 32);
        union { u32 u[4]; bf16x8 v; } f1;
        f1.u[0] = hi ? ycd : x89; f1.u[1] = hi ? yef : xab;
        f1.u[2] = hi ? xcd2 : y89; f1.u[3] = hi ? xef : yab;
        bf16x8 vf1 = *(const bf16x8*)&Vs[lane31 * 420 + jt * 32 + 16 + hi * 8];
        o = __builtin_amdgcn_mfma_f32_32x32x16_bf16(vf1, f1.v, o, 0, 0, 0);
      }
    }
    lsum += __shfl_xor(lsum, 32);
    if (i < FF){
      float linv = 1.f / lsum;
      u16* orow = out + ((size_t)h * NPIX + pi) * 32;   // head-major dense
      #pragma unroll
      for (int g = 0; g < 4; g++){
        int ch0 = g * 8 + hi * 4;
        uint2 st;
        st.x = pkbf(o[g * 4 + 0] * linv, o[g * 4 + 1] * linv);
        st.y = pkbf(o[g * 4 + 2] * linv, o[g * 4 + 3] * linv);
        *(uint2*)&orow[ch0] = st;
      }
    }
  }
}

// ---------------- fused FFN (r13 structure + T5 setprio): fc-chunk 128 ----------------
__global__ __launch_bounds__(256, 3) void ffn_kernel(const u16* __restrict__ xt,
    const u16* __restrict__ w1T, const u16* __restrict__ w2T,
    const float* __restrict__ b1, const float* __restrict__ b2,
    const float* __restrict__ resid, const unsigned char* __restrict__ pmask,
    float* __restrict__ out){
  __shared__ u16 Xs[64 * 256];   // 32 KB, staged with row-XOR pre-swizzle
  __shared__ u16 Hs[64 * 136];   // 17 KB: [p][128f + 8 pad], 272B rows (16B-aligned)
  int t = threadIdx.x, wv = t >> 6, ln = t & 63;
  int q4 = ln >> 4, l15 = ln & 15;
  int p0 = blockIdx.x * 64;
  const char* xb = (const char*)xt + (size_t)p0 * 512;
  #pragma unroll
  for (int it = 0; it < 8; it++){
    int cb = it * 256 + wv * 64;
    int idx = cb + ln;
    int row = idx >> 5, cc = idx & 31;
    gload16(xb + row * 512 + ((cc << 4) ^ ((row & 7) << 4)), (char*)Xs + cb * 16);
  }
  f32x4 acc[4][4];
  #pragma unroll
  for (int r = 0; r < 4; r++)
    #pragma unroll
    for (int c = 0; c < 4; c++) acc[r][c] = (f32x4)0.f;
  int swx = (ln & 7) << 3;
  __syncthreads();
  for (int fc = 0; fc < DFFN; fc += 128){
    f32x4 ha[2][4];
    #pragma unroll
    for (int ft = 0; ft < 2; ft++)
      #pragma unroll
      for (int c = 0; c < 4; c++) ha[ft][c] = (f32x4)0.f;
    const u16* w1f = w1T + ((size_t)((fc >> 4) + wv * 2) * 8 * 64 + ln) * 8;
    __builtin_amdgcn_s_setprio(1);
    #pragma unroll
    for (int kg = 0; kg < 8; kg++){
      bf16x8 aw0 = *(const bf16x8*)(w1f + (size_t)kg * 512);
      bf16x8 aw1 = *(const bf16x8*)(w1f + (size_t)(8 + kg) * 512);
      #pragma unroll
      for (int c = 0; c < 4; c++){
        int p = c * 16 + l15;
        bf16x8 bx = *(const bf16x8*)&Xs[p * 256 + ((kg * 32 + q4 * 8) ^ swx)];
        ha[0][c] = __builtin_amdgcn_mfma_f32_16x16x32_bf16(aw0, bx, ha[0][c], 0, 0, 0);
        ha[1][c] = __builtin_amdgcn_mfma_f32_16x16x32_bf16(aw1, bx, ha[1][c], 0, 0, 0);
      }
    }
    __builtin_amdgcn_s_setprio(0);
    __syncthreads();   // previous phase B done reading Hs
    #pragma unroll
    for (int ft = 0; ft < 2; ft++){
      int f0 = wv * 32 + ft * 16 + q4 * 4;
      f32x4 bv1 = *(const f32x4*)&b1[fc + f0];
      #pragma unroll
      for (int c = 0; c < 4; c++){
        int p = c * 16 + l15;
        uint2 pk;
        pk.x = pkbf(fmaxf(ha[ft][c][0] + bv1[0], 0.f), fmaxf(ha[ft][c][1] + bv1[1], 0.f));
        pk.y = pkbf(fmaxf(ha[ft][c][2] + bv1[2], 0.f), fmaxf(ha[ft][c][3] + bv1[3], 0.f));
        *(uint2*)&Hs[p * 136 + f0] = pk;
      }
    }
    __syncthreads();
    __builtin_amdgcn_s_setprio(1);
    #pragma unroll
    for (int kk2 = 0; kk2 < 4; kk2++){
      bf16x8 a2[4], hb[4];
      #pragma unroll
      for (int r = 0; r < 4; r++)
        a2[r] = *(const bf16x8*)(w2T + ((size_t)((wv * 4 + r) * 64 + (fc >> 5) + kk2) * 64 + ln) * 8);
      #pragma unroll
      for (int c = 0; c < 4; c++)
        hb[c] = *(const bf16x8*)&Hs[(c * 16 + l15) * 136 + kk2 * 32 + q4 * 8];
      #pragma unroll
      for (int r = 0; r < 4; r++)
        #pragma unroll
        for (int c = 0; c < 4; c++)
          acc[r][c] = __builtin_amdgcn_mfma_f32_16x16x32_bf16(a2[r], hb[c], acc[r][c], 0, 0, 0);
    }
    __builtin_amdgcn_s_setprio(0);
  }
  #pragma unroll
  for (int r = 0; r < 4; r++){
    int o0 = wv * 64 + r * 16 + q4 * 4;
    f32x4 bv = *(const f32x4*)&b2[o0];
    #pragma unroll
    for (int c = 0; c < 4; c++){
      int p = p0 + c * 16 + l15;
      int msk = pmask[p];
      #pragma unroll
      for (int q = 0; q < 4; q++){
        size_t oi = (size_t)(o0 + q) * NPIX + p;
        float v = acc[r][c][q] + bv[q] + resid[oi];
        out[oi] = msk ? 0.f : v;
      }
    }
  }
}

extern "C" void kernel_launch(void* const* d_in, const int* in_sizes, int n_in,
                              void* d_out, int out_size, void* d_ws, size_t ws_size,
                              hipStream_t stream){
  const float* src    = (const float*)d_in[0];
  const void*  pmraw  = d_in[1];
  const float* qkv_w  = (const float*)d_in[2];
  const float* qkv_b  = (const float*)d_in[3];
  const float* out_w  = (const float*)d_in[4];
  const float* out_b  = (const float*)d_in[5];
  const float* lin1_w = (const float*)d_in[6];
  const float* lin1_b = (const float*)d_in[7];
  const float* lin2_w = (const float*)d_in[8];
  const float* lin2_b = (const float*)d_in[9];
  const float* n1_g   = (const float*)d_in[10];
  const float* n1_b   = (const float*)d_in[11];
  const float* n2_g   = (const float*)d_in[12];
  const float* n2_b   = (const float*)d_in[13];
  const float* relb   = (const float*)d_in[14];

  char* ws = (char*)d_ws;
  u16* qkvw_bf = (u16*)(ws + OFF_QKVW);
  u16* outw_bf = (u16*)(ws + OFF_OUTW);
  u16* w1_fr   = (u16*)(ws + OFF_W1);
  u16* w2_fr   = (u16*)(ws + OFF_W2);
  int* flag    = (int*)(ws + OFF_FLAG);
  int* wany    = (int*)(ws + OFF_WANY);
  u32* wmaskp  = (u32*)(ws + OFF_WMASK);
  unsigned char* nm = (unsigned char*)(ws + OFF_NM);
  u16* bufA    = (u16*)(ws + OFF_A);   // ln1out/ln2out plain; attnout head-major
  u16* qkvP    = (u16*)(ws + OFF_B);   // qkv planes [24][NPIX][32]
  float* x1    = (float*)(ws + OFF_B); // residual stream f32 (qkvP dead after attn)

  // prep
  cvt_kernel<<<768,  256, 0, stream>>>(qkv_w,  qkvw_bf, 768 * 256);
  cvt_kernel<<<256,  256, 0, stream>>>(out_w,  outw_bf, 256 * 256);
  cvt_w1T<<<2048, 256, 0, stream>>>(lin1_w, w1_fr);
  cvt_w2T<<<2048, 256, 0, stream>>>(lin2_w, w2_fr);
  zero_flag<<<1, 1, 0, stream>>>(flag);
  detect_mask<<<225, 256, 0, stream>>>((const unsigned char*)pmraw, flag);
  norm_mask<<<225, 256, 0, stream>>>(pmraw, flag, nm);
  wmask_kernel<<<144, 512, 0, stream>>>(nm, wmaskp, wany);

  // 1) LN1 -> plain X^T (bufA)
  ln_kernel<<<225, 256, 0, stream>>>(src, n1_g, n1_b, bufA);
  // 2) qkv planes = (W_qkv . X + b) -> [24][NPIX][32] bf16, q pre-scaled
  gemm_nt<2, 0, 6><<<2700, 256, 0, stream>>>(qkvw_bf, bufA, qkv_b, nullptr, (void*)qkvP);
  // 3) MFMA windowed attention (8-wave blocks) -> head-major attnout (bufA)
  attn_kernel<<<1152, 512, 0, stream>>>(qkvP, relb, wmaskp, wany, bufA);
  // 4) out conv + residual -> x1 f32 (region B, qkvP dead); X head-major
  gemm_nt<1, 1, 2><<<900, 256, 0, stream>>>(outw_bf, bufA, out_b, src, (void*)x1);
  // 5) LN2 -> plain X^T (bufA)
  ln_kernel<<<225, 256, 0, stream>>>(x1, n2_g, n2_b, bufA);
  // 6) fused FFN + residual + final mask -> d_out
  ffn_kernel<<<900, 256, 0, stream>>>(bufA, w1_fr, w2_fr, lin1_b, lin2_b, x1, nm,
                                      (float*)d_out);
}

// Round 17
// 523.634 us; speedup vs baseline: 1.0622x; 1.0622x over previous
//
#include <hip/hip_runtime.h>
#include <hip/hip_bf16.h>
#include <math.h>

typedef unsigned short u16;
typedef unsigned int   u32;
typedef __attribute__((ext_vector_type(8))) short bf16x8;
typedef __attribute__((ext_vector_type(4))) float f32x4;
typedef __attribute__((ext_vector_type(16))) float f32x16;
typedef __attribute__((ext_vector_type(4))) u32 u32x4;

#define NSIDE  240
#define NPIX   57600
#define DMODEL 256
#define NHEAD  8
#define HDIM   32
#define LWIN   20
#define NWIN   12
#define FF     400
#define DFFN   2048
#define BTAB   39   // 2*LW-1
#define LOG2E  1.4426950408889634f
#define QSCALE 0.2550773933046f   // 32^-0.5 * log2(e)

// ---- ws layout (bytes) ----
#define OFF_QKVW  0u           // 768*256 bf16 (plain)
#define OFF_OUTW  393216u      // 256*256 bf16 (plain)
#define OFF_W1    524288u      // 2048*256 bf16 (FRAGMENT order)
#define OFF_W2    1572864u     // 256*2048 bf16 (FRAGMENT order)
#define OFF_FLAG  2621440u
#define OFF_WANY  2621504u     // 144 int
#define OFF_WMASK 2622080u     // 144*13 u32
#define OFF_NM    2629568u     // 57600 B
#define OFF_A     2687488u     // 57600*256 bf16: ln1out/ln2out plain [pix][ch]; attnout head-major [h][pix][32]
#define OFF_B     32178688u    // qkv PLANES bf16 [24][NPIX][32]; later x1 f32 [256][NPIX]

__device__ __forceinline__ float bf2f(u16 u){
  union { float f; u32 i; } v; v.i = ((u32)u) << 16; return v.f;
}
__device__ __forceinline__ float bflo(u32 u){
  union { float f; u32 i; } v; v.i = u << 16; return v.f;
}
__device__ __forceinline__ float bfhi(u32 u){
  union { float f; u32 i; } v; v.i = u & 0xffff0000u; return v.f;
}
__device__ __forceinline__ u16 f2bf(float f){
  union { float f; u32 i; } v; v.f = f;
  u32 r = v.i + 0x7fffu + ((v.i >> 16) & 1u);
  return (u16)(r >> 16);
}
__device__ __forceinline__ u32 pkbf(float a, float b){
  float2 f2; f2.x = a; f2.y = b;
  __hip_bfloat162 h = __float22bfloat162_rn(f2);
  union { __hip_bfloat162 h; u32 u; } c; c.h = h; return c.u;
}
__device__ __forceinline__ void gload16(const void* g, void* l){
  __builtin_amdgcn_global_load_lds((const __attribute__((address_space(1))) u32*)g,
                                   (__attribute__((address_space(3))) u32*)l, 16, 0, 0);
}
__device__ __forceinline__ void gload16nt(const void* g, void* l){
  __builtin_amdgcn_global_load_lds((const __attribute__((address_space(1))) u32*)g,
                                   (__attribute__((address_space(3))) u32*)l, 16, 0, 2);
}

// ---------------- prep: f32 -> bf16 weight converts ----------------
__global__ void cvt_kernel(const float* __restrict__ in, u16* __restrict__ out, int n){
  int i = blockIdx.x * 256 + threadIdx.x;
  if (i < n) out[i] = f2bf(in[i]);
}
// W1 [2048f][256k] -> fragment order
__global__ void cvt_w1T(const float* __restrict__ in, u16* __restrict__ out){
  int i = blockIdx.x * 256 + threadIdx.x;   // 2048*256
  int f = i >> 8, k = i & 255;
  int lane = (f & 15) | (((k >> 3) & 3) << 4);
  size_t dst = ((size_t)((f >> 4) * 8 + (k >> 5)) * 64 + lane) * 8 + (k & 7);
  out[dst] = f2bf(in[i]);
}
// W2 [256o][2048f] -> fragment order
__global__ void cvt_w2T(const float* __restrict__ in, u16* __restrict__ out){
  int i = blockIdx.x * 256 + threadIdx.x;   // 256*2048
  int o = i >> 11, f = i & 2047;
  int lane = (o & 15) | (((f >> 3) & 3) << 4);
  size_t dst = ((size_t)((o >> 4) * 64 + (f >> 5)) * 64 + lane) * 8 + (f & 7);
  out[dst] = f2bf(in[i]);
}

// ---------------- mask dtype detect + normalize ----------------
__global__ void zero_flag(int* __restrict__ flag){ *flag = 0; }
__global__ void detect_mask(const unsigned char* __restrict__ m, int* __restrict__ flag){
  int p = blockIdx.x * 256 + threadIdx.x;
  int i = p / NSIDE, j = p - i * NSIDE;
  int a = (m[p] != 0), b = (m[j * NSIDE + i] != 0);
  unsigned long long ball = __ballot(a != b);
  if ((threadIdx.x & 63) == 0 && ball) atomicOr(flag, 1);
}
__global__ void norm_mask(const void* __restrict__ m, const int* __restrict__ flag,
                          unsigned char* __restrict__ nm){
  int p = blockIdx.x * 256 + threadIdx.x;
  int v;
  if (*flag) v = (((const int*)m)[p] != 0);
  else       v = (((const unsigned char*)m)[p] != 0);
  nm[p] = (unsigned char)v;
}

// ---------------- per-window mask bitmaps (with full-window reset) ----------------
__global__ void wmask_kernel(const unsigned char* __restrict__ nm,
                             u32* __restrict__ wmask, int* __restrict__ wany){
  int w = blockIdx.x;
  int wi = w / NWIN, wj = w % NWIN;
  __shared__ u32 bits[13];
  __shared__ int cnt;
  int t = threadIdx.x;
  if (t < 13) bits[t] = 0;
  if (t == 0) cnt = 0;
  __syncthreads();
  if (t < FF){
    int pj = (wi * LWIN + t / LWIN) * NSIDE + wj * LWIN + (t % LWIN);
    if (nm[pj]){ atomicOr(&bits[t >> 5], 1u << (t & 31)); atomicAdd(&cnt, 1); }
  }
  __syncthreads();
  int full = (cnt == FF);
  if (t < 13) wmask[w * 13 + t] = full ? 0u : bits[t];
  if (t == 0) wany[w] = (cnt > 0 && !full) ? 1 : 0;
}

// ---------------- LayerNorm over channels -> X^T [NPIX][256] bf16, PLAIN ----------------
__global__ __launch_bounds__(256) void ln_kernel(const float* __restrict__ x,
                          const float* __restrict__ g, const float* __restrict__ b,
                          u16* __restrict__ out){
  int p = blockIdx.x * 256 + threadIdx.x;
  float s = 0.f, s2 = 0.f;
  for (int c = 0; c < DMODEL; c++){
    float v = x[c * NPIX + p];
    s += v; s2 += v * v;
  }
  float m = s * (1.f / DMODEL);
  float var = s2 * (1.f / DMODEL) - m * m;
  float inv = rsqrtf(var + 1e-5f);
  u16* orow = out + (size_t)p * DMODEL;
  for (int c0 = 0; c0 < DMODEL; c0 += 8){
    u32 wq[4];
    #pragma unroll
    for (int q = 0; q < 4; q++){
      int c = c0 + 2 * q;
      float v0 = (x[c * NPIX + p] - m) * inv * g[c] + b[c];
      float v1 = (x[(c + 1) * NPIX + p] - m) * inv * g[c + 1] + b[c + 1];
      wq[q] = pkbf(v0, v1);
    }
    uint4 st; st.x = wq[0]; st.y = wq[1]; st.z = wq[2]; st.w = wq[3];
    *(uint4*)&orow[c0] = st;
  }
}

// ---------------- MFMA GEMM: C = W[M][256] * X^T ----------------
// 1D grid (MB*450): m0 = (bid%MB)*128, n0 = (bid/MB)*128 -> temporal X-tile L2 reuse.
// XHM=0: X plain [pix][256]. XHM=1: X head-major [h][pix][32] (attnout).
// EPI 1: +bias+res -> f32 [M][NPIX];
// EPI 2: +bias, q-scale, -> bf16 head-major PLANES [plane*8+h][pix][32] via LDS transpose
template<int EPI, int XHM, int MB>
__global__ __launch_bounds__(256) void gemm_nt(const u16* __restrict__ W,
    const u16* __restrict__ Xt, const float* __restrict__ bias,
    const float* __restrict__ res, void* __restrict__ outp){
  __shared__ u16 SM[128 * 128];       // Ws=SM[0:8192], Xs=SM[8192:16384]; epilogue CT
  u16* Ws = SM;
  u16* Xs = SM + 8192;
  int t = threadIdx.x, wv = t >> 6, ln = t & 63;
  int bid = blockIdx.x;
  int m0 = (bid % MB) * 128, n0 = (bid / MB) * 128;
  int wr = wv >> 1, wc = wv & 1;
  f32x4 acc[4][4];
  #pragma unroll
  for (int r = 0; r < 4; r++)
    #pragma unroll
    for (int c = 0; c < 4; c++) acc[r][c] = (f32x4)0.f;
  const char* Wb = (const char*)W;
  const char* Xb = (const char*)Xt;
  for (int k0 = 0; k0 < 256; k0 += 64){
    #pragma unroll
    for (int i = 0; i < 4; i++){
      int cb = i * 256 + wv * 64;          // wave-uniform 16B-chunk base
      int idx = cb + ln;
      int row = idx >> 3, cc = idx & 7;    // 8 chunks (128B) per row
      int cc2 = cc ^ (row & 7);
      gload16(Wb + (size_t)(m0 + row) * 512 + k0 * 2 + (cc2 << 4), (char*)Ws + cb * 16);
      if (XHM){
        int head = (k0 >> 5) + (cc2 >> 2);
        gload16(Xb + ((size_t)head * NPIX + n0 + row) * 64 + ((cc2 & 3) << 4),
                (char*)Xs + cb * 16);
      } else {
        gload16(Xb + (size_t)(n0 + row) * 512 + k0 * 2 + (cc2 << 4), (char*)Xs + cb * 16);
      }
    }
    __syncthreads();
    #pragma unroll
    for (int kk = 0; kk < 64; kk += 32){
      int kidx = kk + (ln >> 4) * 8;
      int swz = (ln & 7) << 3;
      bf16x8 af[4], bfr[4];
      #pragma unroll
      for (int r = 0; r < 4; r++){
        int row = wr * 64 + r * 16 + (ln & 15);
        af[r] = *(const bf16x8*)&Ws[row * 64 + (kidx ^ swz)];
      }
      #pragma unroll
      for (int c = 0; c < 4; c++){
        int row = wc * 64 + c * 16 + (ln & 15);
        bfr[c] = *(const bf16x8*)&Xs[row * 64 + (kidx ^ swz)];
      }
      #pragma unroll
      for (int r = 0; r < 4; r++)
        #pragma unroll
        for (int c = 0; c < 4; c++)
          acc[r][c] = __builtin_amdgcn_mfma_f32_16x16x32_bf16(af[r], bfr[c], acc[r][c], 0, 0, 0);
    }
    __syncthreads();
  }
  if (EPI == 2){
    float sc = (m0 < 256) ? QSCALE : 1.0f;
    #pragma unroll
    for (int r = 0; r < 4; r++){
      int mo0 = wr * 64 + r * 16 + (ln >> 4) * 4;
      f32x4 bv = *(const f32x4*)&bias[m0 + mo0];
      #pragma unroll
      for (int c = 0; c < 4; c++){
        int no = wc * 64 + c * 16 + (ln & 15);
        uint2 pk;
        pk.x = pkbf((acc[r][c][0] + bv[0]) * sc, (acc[r][c][1] + bv[1]) * sc);
        pk.y = pkbf((acc[r][c][2] + bv[2]) * sc, (acc[r][c][3] + bv[3]) * sc);
        *(uint2*)&SM[no * 128 + mo0] = pk;
      }
    }
    __syncthreads();
    u16* ob = (u16*)outp;
    int plane8 = (m0 >> 8) * 8 + ((m0 & 255) >> 5);   // base plane index (q/k/v × head)
    #pragma unroll
    for (int it = 0; it < 8; it++){
      int idx = t + it * 256;
      int pr = idx >> 4, ch = idx & 15;
      int hl = ch >> 2;                  // local head 0..3
      int off = (ch & 3) * 8;            // within-head u16 offset
      uint4 v = *(const uint4*)&SM[pr * 128 + ch * 8];
      *(uint4*)&ob[((size_t)(plane8 + hl) * NPIX + n0 + pr) * 32 + off] = v;
    }
  } else {
    #pragma unroll
    for (int r = 0; r < 4; r++){
      int mo0 = m0 + wr * 64 + r * 16 + (ln >> 4) * 4;
      f32x4 bv = *(const f32x4*)&bias[mo0];
      #pragma unroll
      for (int c = 0; c < 4; c++){
        int no = n0 + wc * 64 + c * 16 + (ln & 15);
        #pragma unroll
        for (int q = 0; q < 4; q++){
          float v = acc[r][c][q] + bv[q];
          size_t oi = (size_t)(mo0 + q) * NPIX + no;
          ((float*)outp)[oi] = v + res[oi];
        }
      }
    }
  }
}

// ---------------- MFMA windowed attention: 512 threads (8 waves), bias from LDS ----------------
// 1D grid 1152; h=bid&7, w=bid>>3. 8 waves share one K/V/bs stage -> 16 waves/CU at
// the same LDS footprint (2 blocks/CU). Bias via identity xj*39+yj = j + 19*xj.
// Output head-major [h][pix][32].
__global__ __launch_bounds__(512, 4) void attn_kernel(
    const u16* __restrict__ qkvP, const float* __restrict__ relb,
    const u32* __restrict__ wmask, const int* __restrict__ wany,
    u16* __restrict__ out)
{
  __shared__ u16 Ks[400 * 32];       // 64B rows; chunk c holds K[j][c ^ (j&3)]
  __shared__ u16 Vs[32 * 420];       // [d][420]; cols 400..415 zeroed
  __shared__ float bs[BTAB * BTAB];  // shifted: bs[a*39+b] = log2e*rel[(a+20)%39][(b+20)%39]
  int bid = blockIdx.x;
  int h = bid & 7, w = bid >> 3;
  int wi = w / NWIN, wj = w % NWIN;
  int t = threadIdx.x, wv = t >> 6, ln = t & 63;
  const char* kpl = (const char*)qkvP + (size_t)(8 + h) * NPIX * 64;
  const u16*  vpl = qkvP + (size_t)(16 + h) * NPIX * 32;
  const u16*  qpl = qkvP + (size_t)h * NPIX * 32;
  // ---- stage bias table ----
  for (int e = t; e < BTAB * BTAB; e += 512){
    int a = e / BTAB, b = e - a * BTAB;
    int r0 = a + 20; if (r0 >= BTAB) r0 -= BTAB;
    int r1 = b + 20; if (r1 >= BTAB) r1 -= BTAB;
    bs[e] = LOG2E * relb[(r0 * BTAB + r1) * NHEAD + h];
  }
  // ---- stage K ----
  #pragma unroll
  for (int it = 0; it < 4; it++){
    int base = it * 512 + wv * 64;
    if (base < 1600){
      int idx = base + ln;
      int j = idx >> 2, c = idx & 3;
      int pj = (wi * LWIN + j / LWIN) * NSIDE + wj * LWIN + (j % LWIN);
      gload16nt(kpl + (size_t)pj * 64 + ((c ^ (j & 3)) << 4), (char*)Ks + base * 16);
    }
  }
  // ---- stage V transposed: j-pair u32 writes ----
  #pragma unroll
  for (int it = 0; it < 2; it++){
    int idx = t + it * 512;
    if (idx >= 832) break;               // 208 j-pairs x 4 channel-chunks
    int jp = idx >> 2, c = idx & 3;
    int j0 = jp * 2;
    int d0 = c * 8;
    u32 a0 = 0, a1 = 0, a2 = 0, a3 = 0, b0 = 0, b1 = 0, b2 = 0, b3 = 0;
    if (j0 < FF){                        // FF even: j0 < FF implies j0+1 < FF
      int pj0 = (wi * LWIN + j0 / LWIN) * NSIDE + wj * LWIN + (j0 % LWIN);
      int j1 = j0 + 1;
      int pj1 = (wi * LWIN + j1 / LWIN) * NSIDE + wj * LWIN + (j1 % LWIN);
      u32x4 va = __builtin_nontemporal_load((const u32x4*)&vpl[(size_t)pj0 * 32 + c * 8]);
      u32x4 vb = __builtin_nontemporal_load((const u32x4*)&vpl[(size_t)pj1 * 32 + c * 8]);
      a0 = va[0]; a1 = va[1]; a2 = va[2]; a3 = va[3];
      b0 = vb[0]; b1 = vb[1]; b2 = vb[2]; b3 = vb[3];
    }
    *(u32*)&Vs[(d0 + 0) * 420 + j0] = (a0 & 0xffffu) | (b0 << 16);
    *(u32*)&Vs[(d0 + 1) * 420 + j0] = (a0 >> 16) | (b0 & 0xffff0000u);
    *(u32*)&Vs[(d0 + 2) * 420 + j0] = (a1 & 0xffffu) | (b1 << 16);
    *(u32*)&Vs[(d0 + 3) * 420 + j0] = (a1 >> 16) | (b1 & 0xffff0000u);
    *(u32*)&Vs[(d0 + 4) * 420 + j0] = (a2 & 0xffffu) | (b2 << 16);
    *(u32*)&Vs[(d0 + 5) * 420 + j0] = (a2 >> 16) | (b2 & 0xffff0000u);
    *(u32*)&Vs[(d0 + 6) * 420 + j0] = (a3 & 0xffffu) | (b3 << 16);
    *(u32*)&Vs[(d0 + 7) * 420 + j0] = (a3 >> 16) | (b3 & 0xffff0000u);
  }
  __syncthreads();
  int lane31 = ln & 31, hi = ln >> 5;
  int anym = wany[w];
  for (int it8 = wv; it8 < 13; it8 += 8){
    int i = it8 * 32 + lane31;
    int ic = i < FF ? i : FF - 1;
    int xi = ic / LWIN, yi = ic - xi * LWIN;
    int pi = (wi * LWIN + xi) * NSIDE + wj * LWIN + yi;
    const float* bsc = bs + (19 - xi) * BTAB + (19 - yi);
    bf16x8 qf0 = __builtin_nontemporal_load((const bf16x8*)&qpl[(size_t)pi * 32 + hi * 8]);
    bf16x8 qf1 = __builtin_nontemporal_load((const bf16x8*)&qpl[(size_t)pi * 32 + 16 + hi * 8]);
    float m = -3e38f, lsum = 0.f;
    f32x16 o;
    #pragma unroll
    for (int r = 0; r < 16; r++) o[r] = 0.f;
    for (int jt = 0; jt < 13; jt++){
      // C-init = bias fragment via LDS gather: idx = j + 19*(j/20)
      f32x16 acc;
      int jbase = jt * 32 + 4 * hi;
      #pragma unroll
      for (int r = 0; r < 16; r++){
        int j = jbase + (r & 3) + 8 * (r >> 2);
        int jc2 = j < FF ? j : 0;
        int xj = jc2 / LWIN;
        float bv = bsc[jc2 + xj * 19];
        acc[r] = (j < FF) ? bv : -1e30f;
      }
      int jb0 = jt * 32 + lane31;
      int jrc = jb0 < FF ? jb0 : FF - 1;
      const char* kb = (const char*)Ks + jrc * 64;
      bf16x8 kf0 = *(const bf16x8*)(kb + ((hi ^ (jrc & 3)) << 4));
      bf16x8 kf1 = *(const bf16x8*)(kb + (((2 + hi) ^ (jrc & 3)) << 4));
      acc = __builtin_amdgcn_mfma_f32_32x32x16_bf16(kf0, qf0, acc, 0, 0, 0);
      acc = __builtin_amdgcn_mfma_f32_32x32x16_bf16(kf1, qf1, acc, 0, 0, 0);
      if (anym){
        u32 mb = wmask[w * 13 + jt];
        if (mb){
          #pragma unroll
          for (int r = 0; r < 16; r++){
            int jb = (r & 3) + 8 * (r >> 2) + 4 * hi;
            if ((mb >> jb) & 1) acc[r] = -1e30f;
          }
        }
      }
      float tm = acc[0];
      #pragma unroll
      for (int r = 1; r < 16; r++) tm = fmaxf(tm, acc[r]);
      tm = fmaxf(tm, __shfl_xor(tm, 32));
      if (tm > m + 6.f){
        float sc = exp2f(m - tm);
        lsum *= sc;
        #pragma unroll
        for (int r = 0; r < 16; r++) o[r] *= sc;
        m = tm;
      }
      float ls = 0.f;
      #pragma unroll
      for (int r = 0; r < 16; r++){ float pv = exp2f(acc[r] - m); acc[r] = pv; ls += pv; }
      lsum += ls;
      u32 x01 = pkbf(acc[0], acc[1]), x23 = pkbf(acc[2], acc[3]);
      u32 x45 = pkbf(acc[4], acc[5]), x67 = pkbf(acc[6], acc[7]);
      u32 y01 = __shfl_xor(x01, 32), y23 = __shfl_xor(x23, 32);
      u32 y45 = __shfl_xor(x45, 32), y67 = __shfl_xor(x67, 32);
      union { u32 u[4]; bf16x8 v; } f0;
      f0.u[0] = hi ? y45 : x01; f0.u[1] = hi ? y67 : x23;
      f0.u[2] = hi ? x45 : y01; f0.u[3] = hi ? x67 : y23;
      bf16x8 vf0 = *(const bf16x8*)&Vs[lane31 * 420 + jt * 32 + hi * 8];
      o = __builtin_amdgcn_mfma_f32_32x32x16_bf16(vf0, f0.v, o, 0, 0, 0);
      if (jt < 12){
        u32 x89 = pkbf(acc[8], acc[9]),   xab = pkbf(acc[10], acc[11]);
        u32 xcd2 = pkbf(acc[12], acc[13]), xef = pkbf(acc[14], acc[15]);
        u32 y89 = __shfl_xor(x89, 32), yab = __shfl_xor(xab, 32);
        u32 ycd = __shfl_xor(xcd2, 32), yef = __shfl_xor(xef, 32);
        union { u32 u[4]; bf16x8 v; } f1;
        f1.u[0] = hi ? ycd : x89; f1.u[1] = hi ? yef : xab;
        f1.u[2] = hi ? xcd2 : y89; f1.u[3] = hi ? xef : yab;
        bf16x8 vf1 = *(const bf16x8*)&Vs[lane31 * 420 + jt * 32 + 16 + hi * 8];
        o = __builtin_amdgcn_mfma_f32_32x32x16_bf16(vf1, f1.v, o, 0, 0, 0);
      }
    }
    lsum += __shfl_xor(lsum, 32);
    if (i < FF){
      float linv = 1.f / lsum;
      u16* orow = out + ((size_t)h * NPIX + pi) * 32;   // head-major dense
      #pragma unroll
      for (int g = 0; g < 4; g++){
        int ch0 = g * 8 + hi * 4;
        uint2 st;
        st.x = pkbf(o[g * 4 + 0] * linv, o[g * 4 + 1] * linv);
        st.y = pkbf(o[g * 4 + 2] * linv, o[g * 4 + 3] * linv);
        *(uint2*)&orow[ch0] = st;
      }
    }
  }
}

// ---------------- fused FFN (r13 version, verbatim): fc-chunk 128, fragment weights ----------------
__global__ __launch_bounds__(256, 3) void ffn_kernel(const u16* __restrict__ xt,
    const u16* __restrict__ w1T, const u16* __restrict__ w2T,
    const float* __restrict__ b1, const float* __restrict__ b2,
    const float* __restrict__ resid, const unsigned char* __restrict__ pmask,
    float* __restrict__ out){
  __shared__ u16 Xs[64 * 256];   // 32 KB, staged with row-XOR pre-swizzle
  __shared__ u16 Hs[64 * 136];   // 17 KB: [p][128f + 8 pad], 272B rows (16B-aligned)
  int t = threadIdx.x, wv = t >> 6, ln = t & 63;
  int q4 = ln >> 4, l15 = ln & 15;
  int p0 = blockIdx.x * 64;
  const char* xb = (const char*)xt + (size_t)p0 * 512;
  #pragma unroll
  for (int it = 0; it < 8; it++){
    int cb = it * 256 + wv * 64;
    int idx = cb + ln;
    int row = idx >> 5, cc = idx & 31;
    gload16(xb + row * 512 + ((cc << 4) ^ ((row & 7) << 4)), (char*)Xs + cb * 16);
  }
  f32x4 acc[4][4];
  #pragma unroll
  for (int r = 0; r < 4; r++)
    #pragma unroll
    for (int c = 0; c < 4; c++) acc[r][c] = (f32x4)0.f;
  int swx = (ln & 7) << 3;
  __syncthreads();
  for (int fc = 0; fc < DFFN; fc += 128){
    f32x4 ha[2][4];
    #pragma unroll
    for (int ft = 0; ft < 2; ft++)
      #pragma unroll
      for (int c = 0; c < 4; c++) ha[ft][c] = (f32x4)0.f;
    const u16* w1f = w1T + ((size_t)((fc >> 4) + wv * 2) * 8 * 64 + ln) * 8;
    #pragma unroll
    for (int kg = 0; kg < 8; kg++){
      bf16x8 aw0 = *(const bf16x8*)(w1f + (size_t)kg * 512);
      bf16x8 aw1 = *(const bf16x8*)(w1f + (size_t)(8 + kg) * 512);
      #pragma unroll
      for (int c = 0; c < 4; c++){
        int p = c * 16 + l15;
        bf16x8 bx = *(const bf16x8*)&Xs[p * 256 + ((kg * 32 + q4 * 8) ^ swx)];
        ha[0][c] = __builtin_amdgcn_mfma_f32_16x16x32_bf16(aw0, bx, ha[0][c], 0, 0, 0);
        ha[1][c] = __builtin_amdgcn_mfma_f32_16x16x32_bf16(aw1, bx, ha[1][c], 0, 0, 0);
      }
    }
    __syncthreads();   // previous phase B done reading Hs
    #pragma unroll
    for (int ft = 0; ft < 2; ft++){
      int f0 = wv * 32 + ft * 16 + q4 * 4;
      f32x4 bv1 = *(const f32x4*)&b1[fc + f0];
      #pragma unroll
      for (int c = 0; c < 4; c++){
        int p = c * 16 + l15;
        uint2 pk;
        pk.x = pkbf(fmaxf(ha[ft][c][0] + bv1[0], 0.f), fmaxf(ha[ft][c][1] + bv1[1], 0.f));
        pk.y = pkbf(fmaxf(ha[ft][c][2] + bv1[2], 0.f), fmaxf(ha[ft][c][3] + bv1[3], 0.f));
        *(uint2*)&Hs[p * 136 + f0] = pk;
      }
    }
    __syncthreads();
    #pragma unroll
    for (int kk2 = 0; kk2 < 4; kk2++){
      bf16x8 a2[4], hb[4];
      #pragma unroll
      for (int r = 0; r < 4; r++)
        a2[r] = *(const bf16x8*)(w2T + ((size_t)((wv * 4 + r) * 64 + (fc >> 5) + kk2) * 64 + ln) * 8);
      #pragma unroll
      for (int c = 0; c < 4; c++)
        hb[c] = *(const bf16x8*)&Hs[(c * 16 + l15) * 136 + kk2 * 32 + q4 * 8];
      #pragma unroll
      for (int r = 0; r < 4; r++)
        #pragma unroll
        for (int c = 0; c < 4; c++)
          acc[r][c] = __builtin_amdgcn_mfma_f32_16x16x32_bf16(a2[r], hb[c], acc[r][c], 0, 0, 0);
    }
  }
  #pragma unroll
  for (int r = 0; r < 4; r++){
    int o0 = wv * 64 + r * 16 + q4 * 4;
    f32x4 bv = *(const f32x4*)&b2[o0];
    #pragma unroll
    for (int c = 0; c < 4; c++){
      int p = p0 + c * 16 + l15;
      int msk = pmask[p];
      #pragma unroll
      for (int q = 0; q < 4; q++){
        size_t oi = (size_t)(o0 + q) * NPIX + p;
        float v = acc[r][c][q] + bv[q] + resid[oi];
        out[oi] = msk ? 0.f : v;
      }
    }
  }
}

extern "C" void kernel_launch(void* const* d_in, const int* in_sizes, int n_in,
                              void* d_out, int out_size, void* d_ws, size_t ws_size,
                              hipStream_t stream){
  const float* src    = (const float*)d_in[0];
  const void*  pmraw  = d_in[1];
  const float* qkv_w  = (const float*)d_in[2];
  const float* qkv_b  = (const float*)d_in[3];
  const float* out_w  = (const float*)d_in[4];
  const float* out_b  = (const float*)d_in[5];
  const float* lin1_w = (const float*)d_in[6];
  const float* lin1_b = (const float*)d_in[7];
  const float* lin2_w = (const float*)d_in[8];
  const float* lin2_b = (const float*)d_in[9];
  const float* n1_g   = (const float*)d_in[10];
  const float* n1_b   = (const float*)d_in[11];
  const float* n2_g   = (const float*)d_in[12];
  const float* n2_b   = (const float*)d_in[13];
  const float* relb   = (const float*)d_in[14];

  char* ws = (char*)d_ws;
  u16* qkvw_bf = (u16*)(ws + OFF_QKVW);
  u16* outw_bf = (u16*)(ws + OFF_OUTW);
  u16* w1_fr   = (u16*)(ws + OFF_W1);
  u16* w2_fr   = (u16*)(ws + OFF_W2);
  int* flag    = (int*)(ws + OFF_FLAG);
  int* wany    = (int*)(ws + OFF_WANY);
  u32* wmaskp  = (u32*)(ws + OFF_WMASK);
  unsigned char* nm = (unsigned char*)(ws + OFF_NM);
  u16* bufA    = (u16*)(ws + OFF_A);   // ln1out/ln2out plain; attnout head-major
  u16* qkvP    = (u16*)(ws + OFF_B);   // qkv planes [24][NPIX][32]
  float* x1    = (float*)(ws + OFF_B); // residual stream f32 (qkvP dead after attn)

  // prep
  cvt_kernel<<<768,  256, 0, stream>>>(qkv_w,  qkvw_bf, 768 * 256);
  cvt_kernel<<<256,  256, 0, stream>>>(out_w,  outw_bf, 256 * 256);
  cvt_w1T<<<2048, 256, 0, stream>>>(lin1_w, w1_fr);
  cvt_w2T<<<2048, 256, 0, stream>>>(lin2_w, w2_fr);
  zero_flag<<<1, 1, 0, stream>>>(flag);
  detect_mask<<<225, 256, 0, stream>>>((const unsigned char*)pmraw, flag);
  norm_mask<<<225, 256, 0, stream>>>(pmraw, flag, nm);
  wmask_kernel<<<144, 512, 0, stream>>>(nm, wmaskp, wany);

  // 1) LN1 -> plain X^T (bufA)
  ln_kernel<<<225, 256, 0, stream>>>(src, n1_g, n1_b, bufA);
  // 2) qkv planes = (W_qkv . X + b) -> [24][NPIX][32] bf16, q pre-scaled
  gemm_nt<2, 0, 6><<<2700, 256, 0, stream>>>(qkvw_bf, bufA, qkv_b, nullptr, (void*)qkvP);
  // 3) MFMA windowed attention (8-wave blocks) -> head-major attnout (bufA)
  attn_kernel<<<1152, 512, 0, stream>>>(qkvP, relb, wmaskp, wany, bufA);
  // 4) out conv + residual -> x1 f32 (region B, qkvP dead); X head-major
  gemm_nt<1, 1, 2><<<900, 256, 0, stream>>>(outw_bf, bufA, out_b, src, (void*)x1);
  // 5) LN2 -> plain X^T (bufA)
  ln_kernel<<<225, 256, 0, stream>>>(x1, n2_g, n2_b, bufA);
  // 6) fused FFN + residual + final mask -> d_out
  ffn_kernel<<<900, 256, 0, stream>>>(bufA, w1_fr, w2_fr, lin1_b, lin2_b, x1, nm,
                                      (float*)d_out);
}